// Round 2
// baseline (193.225 us; speedup 1.0000x reference)
//
#include <hip/hip_runtime.h>

// CRF loss: mean_b( log Z_b - score_b ),  B=128, S=512, T=64 (mask all-ones).
//
// K2 (scan): forward algorithm in LINEAR space, 16 batches per wave via MFMA.
//   D = A * B : A = exp(trans) rearranged (loop-invariant, registers),
//               B = P^T (K=prev state, N=batch), D = new P (pre-emission).
//   A column permutation pi baked into A makes D's register layout equal the
//   next step's B layout up to in-lane renaming (no cross-lane ops per step).
//   Exact power-of-2 rescale every 8 steps. Producer wave streams exp(em)
//   through a 4-slot LDS ring (raw s_barrier + lgkmcnt only; global loads
//   stay in flight across barriers).

#define BB 128
#define SS 512
#define TT 64

typedef float f32x4 __attribute__((ext_vector_type(4)));
typedef short s16x8 __attribute__((ext_vector_type(8)));

#define MFMA16(a, b, c) __builtin_amdgcn_mfma_f32_16x16x32_bf16((a), (b), (c), 0, 0, 0)

__device__ __forceinline__ unsigned pack_bf16_trunc(float hi, float lo) {
    // dst = (trunc_bf16(hi) << 16) | trunc_bf16(lo)
    return __builtin_amdgcn_perm(__float_as_uint(hi), __float_as_uint(lo), 0x07060302u);
}
__device__ __forceinline__ unsigned short bf16_rne(float x) {
    unsigned u = __float_as_uint(x);
    u += 0x7FFFu + ((u >> 16) & 1u);
    return (unsigned short)(u >> 16);
}

// ---------------- K1: path score (numerator), one wave per batch ----------------
__global__ __launch_bounds__(64) void crf_score_kernel(
    const float* __restrict__ emissions, const float* __restrict__ transitions,
    const float* __restrict__ start_t, const float* __restrict__ end_t,
    const int* __restrict__ tags, float* __restrict__ ws)
{
    const int b = blockIdx.x;
    const int j = threadIdx.x;
    const float* em = emissions + (size_t)b * SS * TT;
    float sc = 0.f;
    #pragma unroll
    for (int r = 0; r < SS / TT; ++r) {
        int i = j + r * TT;
        int cur = tags[b * SS + i];
        if (i > 0) {
            int prev = tags[b * SS + i - 1];
            sc += transitions[prev * TT + cur] + em[i * TT + cur];
        } else {
            sc += start_t[cur] + em[cur];
        }
    }
    if (j == 0) sc += end_t[tags[b * SS + SS - 1]];
    #pragma unroll
    for (int s = 1; s < 64; s <<= 1) sc += __shfl_xor(sc, s, 64);
    if (j == 0) ws[b] = sc;
}

// ---------------- K2: forward scan, 16 batches/wave, producer+consumer ----------------
__global__ __launch_bounds__(128) void crf_scan_kernel(
    const float* __restrict__ emissions, const float* __restrict__ transitions,
    const float* __restrict__ start_t, const float* __restrict__ end_t,
    float* __restrict__ ws)
{
    __shared__ float eem_lds[4 * 4 * 64 * 4];   // [slot][w4][lane][4] = 16 KB
    const float LOG2E = 1.4426950408889634f;
    const float LN2   = 0.6931471805599453f;
    const int tid = threadIdx.x;
    const int l   = tid & 63;
    const int g   = l >> 4;
    const int m   = l & 15;
    const int b   = (blockIdx.x << 4) + m;      // batch for this lane's column
    const float* emb = emissions + (size_t)b * (SS * TT);

    if (tid < 64) {
        // =================== CONSUMER wave ===================
        // A fragments: A[t][h] elem j = bf16(exp(trans[k][pi(16t+m)])), k=32h+8g+j
        // pi(16t+m) = 8*(m>>2) + 4*(t&1) + (m&3) + 32*(t>>1)
        s16x8 A[4][2];
        #pragma unroll
        for (int t = 0; t < 4; ++t) {
            const int ps = 8 * (m >> 2) + 4 * (t & 1) + (m & 3) + 32 * (t >> 1);
            #pragma unroll
            for (int h = 0; h < 2; ++h) {
                union { s16x8 v; unsigned short s[8]; } u;
                #pragma unroll
                for (int j = 0; j < 8; ++j) {
                    int k = 32 * h + 8 * g + j;
                    u.s[j] = bf16_rne(exp2f(transitions[k * TT + ps] * LOG2E));
                }
                A[t][h] = u.v;
            }
        }
        // P0 = exp(start + em[0]) packed into B fragments (k = 8g+j / 32+8g+j)
        union { s16x8 v; unsigned u32[4]; } Blo, Bhi;
        #pragma unroll
        for (int r = 0; r < 4; ++r) {
            int s0 = 8 * g + 2 * r;
            float plo = exp2f((start_t[s0]     + emb[s0])     * LOG2E);
            float phi = exp2f((start_t[s0 + 1] + emb[s0 + 1]) * LOG2E);
            Blo.u32[r] = pack_bf16_trunc(phi, plo);
            int s1 = 32 + 8 * g + 2 * r;
            float qlo = exp2f((start_t[s1]     + emb[s1])     * LOG2E);
            float qhi = exp2f((start_t[s1 + 1] + emb[s1 + 1]) * LOG2E);
            Bhi.u32[r] = pack_bf16_trunc(qhi, qlo);
        }
        const f32x4 Z = {0.f, 0.f, 0.f, 0.f};
        f32x4 d0 = Z, d1 = Z, d2 = Z, d3 = Z;
        f32x4 eemA[4], eemB[4];
        int eoff = 0;

        asm volatile("" ::: "memory");
        __builtin_amdgcn_s_barrier();            // barrier #0
        asm volatile("" ::: "memory");
        // eem for step 1 (slot 1)
        eemA[0] = *(const f32x4*)&eem_lds[((1 * 4 + 0) * 64 + l) * 4];
        eemA[1] = *(const f32x4*)&eem_lds[((1 * 4 + 1) * 64 + l) * 4];
        eemA[2] = *(const f32x4*)&eem_lds[((1 * 4 + 2) * 64 + l) * 4];
        eemA[3] = *(const f32x4*)&eem_lds[((1 * 4 + 3) * 64 + l) * 4];

#define CSTEP(SLOTN, RESC, CUR, NXT) do {                                        \
    NXT[0] = *(const f32x4*)&eem_lds[(((SLOTN) * 4 + 0) * 64 + l) * 4];          \
    NXT[1] = *(const f32x4*)&eem_lds[(((SLOTN) * 4 + 1) * 64 + l) * 4];          \
    NXT[2] = *(const f32x4*)&eem_lds[(((SLOTN) * 4 + 2) * 64 + l) * 4];          \
    NXT[3] = *(const f32x4*)&eem_lds[(((SLOTN) * 4 + 3) * 64 + l) * 4];          \
    f32x4 c0 = MFMA16(A[0][0], Blo.v, Z);                                        \
    f32x4 c1 = MFMA16(A[1][0], Blo.v, Z);                                        \
    f32x4 c2 = MFMA16(A[2][0], Blo.v, Z);                                        \
    f32x4 c3 = MFMA16(A[3][0], Blo.v, Z);                                        \
    c0 = MFMA16(A[0][1], Bhi.v, c0);                                             \
    c1 = MFMA16(A[1][1], Bhi.v, c1);                                             \
    c2 = MFMA16(A[2][1], Bhi.v, c2);                                             \
    c3 = MFMA16(A[3][1], Bhi.v, c3);                                             \
    d0 = c0 * CUR[0]; d1 = c1 * CUR[1]; d2 = c2 * CUR[2]; d3 = c3 * CUR[3];      \
    if (RESC) {                                                                  \
        float mx = fmaxf(fmaxf(fmaxf(d0[0], d0[1]), fmaxf(d0[2], d0[3])),        \
                         fmaxf(fmaxf(d1[0], d1[1]), fmaxf(d1[2], d1[3])));       \
        mx = fmaxf(mx, fmaxf(fmaxf(fmaxf(d2[0], d2[1]), fmaxf(d2[2], d2[3])),    \
                             fmaxf(fmaxf(d3[0], d3[1]), fmaxf(d3[2], d3[3])))); \
        mx = fmaxf(mx, __shfl_xor(mx, 16));                                      \
        mx = fmaxf(mx, __shfl_xor(mx, 32));                                      \
        int e_ = (__float_as_int(mx) >> 23) - 127;                               \
        eoff += e_;                                                              \
        float sc_ = __int_as_float((127 - e_) << 23);                            \
        d0 *= sc_; d1 *= sc_; d2 *= sc_; d3 *= sc_;                              \
    }                                                                            \
    Blo.u32[0] = pack_bf16_trunc(d0[1], d0[0]);                                  \
    Blo.u32[1] = pack_bf16_trunc(d0[3], d0[2]);                                  \
    Blo.u32[2] = pack_bf16_trunc(d1[1], d1[0]);                                  \
    Blo.u32[3] = pack_bf16_trunc(d1[3], d1[2]);                                  \
    Bhi.u32[0] = pack_bf16_trunc(d2[1], d2[0]);                                  \
    Bhi.u32[1] = pack_bf16_trunc(d2[3], d2[2]);                                  \
    Bhi.u32[2] = pack_bf16_trunc(d3[1], d3[0]);                                  \
    Bhi.u32[3] = pack_bf16_trunc(d3[3], d3[2]);                                  \
    asm volatile("" ::: "memory");                                               \
    __builtin_amdgcn_s_barrier();                                                \
    asm volatile("" ::: "memory");                                               \
} while (0)

        for (int blk = 0; blk < 63; ++blk) {     // steps 1..504
            CSTEP(2, 0, eemA, eemB);
            CSTEP(3, 0, eemB, eemA);
            CSTEP(0, 0, eemA, eemB);
            CSTEP(1, 0, eemB, eemA);
            CSTEP(2, 0, eemA, eemB);
            CSTEP(3, 0, eemB, eemA);
            CSTEP(0, 0, eemA, eemB);
            CSTEP(1, 1, eemB, eemA);             // i % 8 == 0: rescale
        }
        // tail steps 505..511
        CSTEP(2, 0, eemA, eemB);
        CSTEP(3, 0, eemB, eemA);
        CSTEP(0, 0, eemA, eemB);
        CSTEP(1, 0, eemB, eemA);
        CSTEP(2, 0, eemA, eemB);
        CSTEP(3, 0, eemB, eemA);
        CSTEP(0, 0, eemA, eemB);                 // i = 511
#undef CSTEP

        // epilogue: logsumexp(alpha + end)
        float vsum = 0.f;
        #pragma unroll
        for (int t = 0; t < 4; ++t) {
            #pragma unroll
            for (int r = 0; r < 4; ++r) {
                int s = 8 * g + 4 * (t & 1) + r + 32 * (t >> 1);
                float dv = (t == 0) ? d0[r] : (t == 1) ? d1[r] : (t == 2) ? d2[r] : d3[r];
                vsum += dv * exp2f(end_t[s] * LOG2E);
            }
        }
        vsum += __shfl_xor(vsum, 16);
        vsum += __shfl_xor(vsum, 32);
        float denom = (log2f(vsum) + (float)eoff) * LN2;
        if (l < 16) ws[BB + b] = denom - ws[b];
    } else {
        // =================== PRODUCER wave ===================
        f32x4 raw[4][4];

#define PLOAD(S, Bf) do {                                                        \
    const float* p_ = emb + (size_t)(S) * TT + 8 * g;                            \
    raw[Bf][0] = *(const f32x4*)(p_);                                            \
    raw[Bf][1] = *(const f32x4*)(p_ + 4);                                        \
    raw[Bf][2] = *(const f32x4*)(p_ + 32);                                       \
    raw[Bf][3] = *(const f32x4*)(p_ + 36);                                       \
} while (0)
#define PEXPW(SB) do {                                                           \
    f32x4 x0 = raw[SB][0], x1 = raw[SB][1], x2 = raw[SB][2], x3 = raw[SB][3];    \
    f32x4 y0, y1, y2, y3;                                                        \
    y0[0] = exp2f(x0[0] * LOG2E); y0[1] = exp2f(x0[1] * LOG2E);                  \
    y0[2] = exp2f(x0[2] * LOG2E); y0[3] = exp2f(x0[3] * LOG2E);                  \
    y1[0] = exp2f(x1[0] * LOG2E); y1[1] = exp2f(x1[1] * LOG2E);                  \
    y1[2] = exp2f(x1[2] * LOG2E); y1[3] = exp2f(x1[3] * LOG2E);                  \
    y2[0] = exp2f(x2[0] * LOG2E); y2[1] = exp2f(x2[1] * LOG2E);                  \
    y2[2] = exp2f(x2[2] * LOG2E); y2[3] = exp2f(x2[3] * LOG2E);                  \
    y3[0] = exp2f(x3[0] * LOG2E); y3[1] = exp2f(x3[1] * LOG2E);                  \
    y3[2] = exp2f(x3[2] * LOG2E); y3[3] = exp2f(x3[3] * LOG2E);                  \
    *(f32x4*)&eem_lds[(((SB) * 4 + 0) * 64 + l) * 4] = y0;                       \
    *(f32x4*)&eem_lds[(((SB) * 4 + 1) * 64 + l) * 4] = y1;                       \
    *(f32x4*)&eem_lds[(((SB) * 4 + 2) * 64 + l) * 4] = y2;                       \
    *(f32x4*)&eem_lds[(((SB) * 4 + 3) * 64 + l) * 4] = y3;                       \
} while (0)
#define PBAR() do {                                                              \
    asm volatile("s_waitcnt lgkmcnt(0)" ::: "memory");                           \
    __builtin_amdgcn_s_barrier();                                                \
    asm volatile("" ::: "memory");                                               \
} while (0)
#define PSTEP(SB, S, DW) do { if (DW) PEXPW(SB); PLOAD(S, SB); PBAR(); } while (0)

        // prologue: fill slots for steps 1,2; prime raw bufs for steps 3..6
        PLOAD(1, 1); PLOAD(2, 2);
        PEXPW(1); PEXPW(2);
        PLOAD(3, 3); PLOAD(4, 0); PLOAD(5, 1); PLOAD(6, 2);
        PBAR();                                  // barrier #0

        for (int blk = 0; blk < 63; ++blk) {     // steps 1..504
            const int ib = 8 * blk + 1;
            PSTEP(3, ib + 6, 1);
            PSTEP(0, ib + 7, 1);
            PSTEP(1, ib + 8, 1);
            PSTEP(2, ib + 9, 1);
            PSTEP(3, ib + 10, 1);
            PSTEP(0, ib + 11, 1);
            PSTEP(1, ib + 12, 1);
            PSTEP(2, ib + 13, 1);
        }
        // tail steps 505..511: write slots for 507..511, clamp loads
        PSTEP(3, 511, 1);
        PSTEP(0, 511, 1);
        PSTEP(1, 511, 1);
        PSTEP(2, 511, 1);
        PSTEP(3, 511, 1);
        PSTEP(0, 511, 0);
        PSTEP(1, 511, 0);
#undef PSTEP
#undef PBAR
#undef PEXPW
#undef PLOAD
    }
}

// ---------------- K3: final mean ----------------
__global__ __launch_bounds__(64) void crf_reduce_kernel(
    const float* __restrict__ ws, float* __restrict__ out)
{
    int l = threadIdx.x;
    float v = ws[BB + l] + ws[BB + l + 64];
    #pragma unroll
    for (int s = 1; s < 64; s <<= 1) v += __shfl_xor(v, s, 64);
    if (l == 0) out[0] = v * (1.0f / (float)BB);
}

extern "C" void kernel_launch(void* const* d_in, const int* in_sizes, int n_in,
                              void* d_out, int out_size, void* d_ws, size_t ws_size,
                              hipStream_t stream) {
    const float* emissions   = (const float*)d_in[0];
    const float* transitions = (const float*)d_in[1];
    const float* start_t     = (const float*)d_in[2];
    const float* end_t       = (const float*)d_in[3];
    const int*   tags        = (const int*)d_in[4];
    float* ws = (float*)d_ws;

    crf_score_kernel<<<BB, 64, 0, stream>>>(emissions, transitions, start_t,
                                            end_t, tags, ws);
    crf_scan_kernel<<<BB / 16, 128, 0, stream>>>(emissions, transitions, start_t,
                                                 end_t, ws);
    crf_reduce_kernel<<<1, 64, 0, stream>>>(ws, (float*)d_out);
}

// Round 3
// 111.085 us; speedup vs baseline: 1.7394x; 1.7394x over previous
//
#include <hip/hip_runtime.h>

// CRF loss: mean_b( log Z_b - score_b ),  B=128, S=512, T=64 (mask all-ones).
//
// Parallel associative scan over the sequence:
//   alpha_511 = alpha_0 * PROD_{i=1..511} (E * diag(eem_i)),  E = exp(trans)
// Phase 1 (crf_chunk_kernel): 8 chunks x 128 batches = 1024 independent waves;
//   each computes its chunk's 64x64 transfer matrix M_c by running the
//   R1-verified MFMA recurrence on 64 identity basis columns (4 n-blocks of
//   16). eem computed in-wave; rescale folded into the next step's exp2 as an
//   exponent subtraction (exact pow2). No barriers, no LDS.
// Phase 2 (crf_combine_kernel): one wave per batch chains alpha through the
//   8 stored bf16 matrices (readlane-FMA), then logsumexp with end_t.

#define BB 128
#define SS 512
#define TT 64

typedef float f32x4 __attribute__((ext_vector_type(4)));
typedef short s16x8 __attribute__((ext_vector_type(8)));
typedef unsigned int u32x4 __attribute__((ext_vector_type(4)));

#define MFMA16(a, b, c) __builtin_amdgcn_mfma_f32_16x16x32_bf16((a), (b), (c), 0, 0, 0)

#define LOG2E 1.4426950408889634f
#define LN2   0.6931471805599453f

__device__ __forceinline__ unsigned pack_bf16_trunc(float hi, float lo) {
    return __builtin_amdgcn_perm(__float_as_uint(hi), __float_as_uint(lo), 0x07060302u);
}
__device__ __forceinline__ unsigned short bf16_rne(float x) {
    unsigned u = __float_as_uint(x);
    u += 0x7FFFu + ((u >> 16) & 1u);
    return (unsigned short)(u >> 16);
}
__device__ __forceinline__ float rdlane(float v, int lane) {
    return __uint_as_float(__builtin_amdgcn_readlane(__float_as_uint(v), lane));
}

// ---------------- K1: path score (numerator), one wave per batch ----------------
__global__ __launch_bounds__(64) void crf_score_kernel(
    const float* __restrict__ emissions, const float* __restrict__ transitions,
    const float* __restrict__ start_t, const float* __restrict__ end_t,
    const int* __restrict__ tags, float* __restrict__ score)
{
    const int b = blockIdx.x;
    const int j = threadIdx.x;
    const float* em = emissions + (size_t)b * SS * TT;
    float sc = 0.f;
    #pragma unroll
    for (int r = 0; r < SS / TT; ++r) {
        int i = j + r * TT;
        int cur = tags[b * SS + i];
        if (i > 0) {
            int prev = tags[b * SS + i - 1];
            sc += transitions[prev * TT + cur] + em[i * TT + cur];
        } else {
            sc += start_t[cur] + em[cur];
        }
    }
    if (j == 0) sc += end_t[tags[b * SS + SS - 1]];
    #pragma unroll
    for (int s = 1; s < 64; s <<= 1) sc += __shfl_xor(sc, s, 64);
    if (j == 0) score[b] = sc;
}

// ---------------- Phase 1: chunk transfer matrices ----------------
template<int L>
__device__ __forceinline__ void chunk_body(
    const float* __restrict__ emb, int sbase,
    const s16x8 A[4][2],
    unsigned short* __restrict__ Mout,   // this chunk's 64x64 bf16 matrix
    int* __restrict__ eoff_out,
    int g, int m, int l)
{
    const f32x4 Z = {0.f, 0.f, 0.f, 0.f};
    // Identity init: column (16*nb + m) of the basis; B-frag slot (g, pair r)
    // covers k = 8g+2r (+1) for Blo, 32+8g+2r (+1) for Bhi.
    union BU { s16x8 v; unsigned u[4]; };
    BU Blo[4], Bhi[4];
    #pragma unroll
    for (int nb = 0; nb < 4; ++nb) {
        const int K = 16 * nb + m;
        #pragma unroll
        for (int r = 0; r < 4; ++r) {
            int k0 = 8 * g + 2 * r;
            Blo[nb].u[r] = ((k0 == K) ? 0x3F80u : 0u) | ((k0 + 1 == K) ? 0x3F800000u : 0u);
            int k1 = 32 + 8 * g + 2 * r;
            Bhi[nb].u[r] = ((k1 == K) ? 0x3F80u : 0u) | ((k1 + 1 == K) ? 0x3F800000u : 0u);
        }
    }

    // em prefetch ring, 3 steps deep
    f32x4 raw[3][4];
    #pragma unroll
    for (int i = 0; i < 3; ++i) {
        const float* p = emb + (size_t)(sbase + i) * TT + 8 * g;
        raw[i][0] = *(const f32x4*)(p);
        raw[i][1] = *(const f32x4*)(p + 4);
        raw[i][2] = *(const f32x4*)(p + 32);
        raw[i][3] = *(const f32x4*)(p + 36);
    }

    f32x4 d[4][4];
    int eoff = 0;
    int epend = 0;

    #pragma unroll
    for (int i = 0; i < L; ++i) {
        const int s = i % 3;
        f32x4 r0 = raw[s][0], r1 = raw[s][1], r2 = raw[s][2], r3 = raw[s][3];
        // prefetch step i+3 into the freed slot
        int sp = sbase + i + 3; if (sp > SS - 1) sp = SS - 1;
        {
            const float* p = emb + (size_t)sp * TT + 8 * g;
            raw[s][0] = *(const f32x4*)(p);
            raw[s][1] = *(const f32x4*)(p + 4);
            raw[s][2] = *(const f32x4*)(p + 32);
            raw[s][3] = *(const f32x4*)(p + 36);
        }
        // eem with folded pow2 rescale: exp2(em*log2e - epend)
        const float fne = -(float)epend;
        epend = 0;
        f32x4 CUR[4];
        #pragma unroll
        for (int r = 0; r < 4; ++r) {
            CUR[0][r] = exp2f(fmaf(r0[r], LOG2E, fne));
            CUR[1][r] = exp2f(fmaf(r1[r], LOG2E, fne));
            CUR[2][r] = exp2f(fmaf(r2[r], LOG2E, fne));
            CUR[3][r] = exp2f(fmaf(r3[r], LOG2E, fne));
        }
        #pragma unroll
        for (int nb = 0; nb < 4; ++nb) {
            f32x4 c0 = MFMA16(A[0][0], Blo[nb].v, Z);
            f32x4 c1 = MFMA16(A[1][0], Blo[nb].v, Z);
            f32x4 c2 = MFMA16(A[2][0], Blo[nb].v, Z);
            f32x4 c3 = MFMA16(A[3][0], Blo[nb].v, Z);
            c0 = MFMA16(A[0][1], Bhi[nb].v, c0);
            c1 = MFMA16(A[1][1], Bhi[nb].v, c1);
            c2 = MFMA16(A[2][1], Bhi[nb].v, c2);
            c3 = MFMA16(A[3][1], Bhi[nb].v, c3);
            d[nb][0] = c0 * CUR[0];
            d[nb][1] = c1 * CUR[1];
            d[nb][2] = c2 * CUR[2];
            d[nb][3] = c3 * CUR[3];
        }
        if (i == L - 1) break;
        if ((i & 7) == 7) {
            // wave-wide max -> pending exponent for next step's CUR
            float mx = d[0][0][0];
            #pragma unroll
            for (int nb = 0; nb < 4; ++nb)
                #pragma unroll
                for (int t = 0; t < 4; ++t) {
                    f32x4 v = d[nb][t];
                    mx = fmaxf(mx, fmaxf(fmaxf(v[0], v[1]), fmaxf(v[2], v[3])));
                }
            #pragma unroll
            for (int sh = 1; sh < 64; sh <<= 1) mx = fmaxf(mx, __shfl_xor(mx, sh, 64));
            int e = (__float_as_int(mx) >> 23) - 127;
            eoff += e;
            epend = e;
        }
        // repack d -> next B fragments (R1-verified mapping)
        #pragma unroll
        for (int nb = 0; nb < 4; ++nb) {
            Blo[nb].u[0] = pack_bf16_trunc(d[nb][0][1], d[nb][0][0]);
            Blo[nb].u[1] = pack_bf16_trunc(d[nb][0][3], d[nb][0][2]);
            Blo[nb].u[2] = pack_bf16_trunc(d[nb][1][1], d[nb][1][0]);
            Blo[nb].u[3] = pack_bf16_trunc(d[nb][1][3], d[nb][1][2]);
            Bhi[nb].u[0] = pack_bf16_trunc(d[nb][2][1], d[nb][2][0]);
            Bhi[nb].u[1] = pack_bf16_trunc(d[nb][2][3], d[nb][2][2]);
            Bhi[nb].u[2] = pack_bf16_trunc(d[nb][3][1], d[nb][3][0]);
            Bhi[nb].u[3] = pack_bf16_trunc(d[nb][3][3], d[nb][3][2]);
        }
    }

    // final exact-pow2 normalize and store M[k][j] (k = basis = 16nb+m,
    // j = state = 8g + 4(t&1) + r + 32(t>>1))
    float mx = d[0][0][0];
    #pragma unroll
    for (int nb = 0; nb < 4; ++nb)
        #pragma unroll
        for (int t = 0; t < 4; ++t) {
            f32x4 v = d[nb][t];
            mx = fmaxf(mx, fmaxf(fmaxf(v[0], v[1]), fmaxf(v[2], v[3])));
        }
    #pragma unroll
    for (int sh = 1; sh < 64; sh <<= 1) mx = fmaxf(mx, __shfl_xor(mx, sh, 64));
    int e = (__float_as_int(mx) >> 23) - 127;
    eoff += e;
    const float sc = __int_as_float((127 - e) << 23);
    #pragma unroll
    for (int nb = 0; nb < 4; ++nb) {
        f32x4 d0 = d[nb][0] * sc, d1 = d[nb][1] * sc, d2 = d[nb][2] * sc, d3 = d[nb][3] * sc;
        const int row = (16 * nb + m) * TT;
        u32x4 w0, w1;
        w0[0] = pack_bf16_trunc(d0[1], d0[0]);
        w0[1] = pack_bf16_trunc(d0[3], d0[2]);
        w0[2] = pack_bf16_trunc(d1[1], d1[0]);
        w0[3] = pack_bf16_trunc(d1[3], d1[2]);
        w1[0] = pack_bf16_trunc(d2[1], d2[0]);
        w1[1] = pack_bf16_trunc(d2[3], d2[2]);
        w1[2] = pack_bf16_trunc(d3[1], d3[0]);
        w1[3] = pack_bf16_trunc(d3[3], d3[2]);
        *(u32x4*)(Mout + row + 8 * g)      = w0;
        *(u32x4*)(Mout + row + 32 + 8 * g) = w1;
    }
    if (l == 0) *eoff_out = eoff;
}

__global__ __launch_bounds__(256, 1) void crf_chunk_kernel(
    const float* __restrict__ emissions, const float* __restrict__ transitions,
    unsigned short* __restrict__ M, int* __restrict__ eoffs)
{
    const int tid = threadIdx.x;
    const int l = tid & 63;
    const int w = tid >> 6;
    const int g = l >> 4;
    const int m = l & 15;
    const int b = blockIdx.x >> 1;
    const int c = ((blockIdx.x & 1) << 2) + w;
    const float* emb = emissions + (size_t)b * SS * TT;

    // A fragments (R1-verified): A[t][h] elem j = bf16(exp(trans[k][ps])),
    // k = 32h + 8g + j, ps = 8*(m>>2) + 4*(t&1) + (m&3) + 32*(t>>1)
    s16x8 A[4][2];
    #pragma unroll
    for (int t = 0; t < 4; ++t) {
        const int ps = 8 * (m >> 2) + 4 * (t & 1) + (m & 3) + 32 * (t >> 1);
        #pragma unroll
        for (int h = 0; h < 2; ++h) {
            union { s16x8 v; unsigned short s[8]; } u;
            #pragma unroll
            for (int j = 0; j < 8; ++j) {
                int k = 32 * h + 8 * g + j;
                u.s[j] = bf16_rne(exp2f(transitions[k * TT + ps] * LOG2E));
            }
            A[t][h] = u.v;
        }
    }

    unsigned short* Mout = M + (size_t)(b * 8 + c) * (TT * TT);
    int* eo = eoffs + b * 8 + c;
    const int sbase = 64 * c + 1;
    if (c == 7) chunk_body<63>(emb, sbase, A, Mout, eo, g, m, l);
    else        chunk_body<64>(emb, sbase, A, Mout, eo, g, m, l);
}

// ---------------- Phase 2: chain alpha through the 8 chunk matrices ----------------
__global__ __launch_bounds__(64) void crf_combine_kernel(
    const float* __restrict__ emissions, const float* __restrict__ start_t,
    const float* __restrict__ end_t, const unsigned short* __restrict__ M,
    const int* __restrict__ eoffs, const float* __restrict__ score,
    float* __restrict__ res)
{
    const int b = blockIdx.x;
    const int j = threadIdx.x;
    float a = exp2f((start_t[j] + emissions[(size_t)b * SS * TT + j]) * LOG2E);
    int eoff = 0;
    #pragma unroll
    for (int c = 0; c < 8; ++c) {
        const unsigned short* Mc = M + (size_t)(b * 8 + c) * (TT * TT) + j;
        float acc = 0.f;
        #pragma unroll
        for (int k = 0; k < TT; ++k) {
            float mv = __uint_as_float(((unsigned)Mc[k * TT]) << 16);
            acc = fmaf(rdlane(a, k), mv, acc);
        }
        float mxv = acc;
        #pragma unroll
        for (int sh = 1; sh < 64; sh <<= 1) mxv = fmaxf(mxv, __shfl_xor(mxv, sh, 64));
        int e = (__float_as_int(mxv) >> 23) - 127;
        a = acc * __int_as_float((127 - e) << 23);
        eoff += e + eoffs[b * 8 + c];
    }
    float v = a * exp2f(end_t[j] * LOG2E);
    #pragma unroll
    for (int sh = 1; sh < 64; sh <<= 1) v += __shfl_xor(v, sh, 64);
    if (j == 0) res[b] = (log2f(v) + (float)eoff) * LN2 - score[b];
}

// ---------------- K4: final mean ----------------
__global__ __launch_bounds__(64) void crf_reduce_kernel(
    const float* __restrict__ res, float* __restrict__ out)
{
    int l = threadIdx.x;
    float v = res[l] + res[l + 64];
    #pragma unroll
    for (int s = 1; s < 64; s <<= 1) v += __shfl_xor(v, s, 64);
    if (l == 0) out[0] = v * (1.0f / (float)BB);
}

extern "C" void kernel_launch(void* const* d_in, const int* in_sizes, int n_in,
                              void* d_out, int out_size, void* d_ws, size_t ws_size,
                              hipStream_t stream) {
    const float* emissions   = (const float*)d_in[0];
    const float* transitions = (const float*)d_in[1];
    const float* start_t     = (const float*)d_in[2];
    const float* end_t       = (const float*)d_in[3];
    const int*   tags        = (const int*)d_in[4];

    float* wsf  = (float*)d_ws;
    float* score = wsf;                                   // [0..127]
    float* res   = wsf + 128;                             // [128..255]
    int*   eoffs = (int*)(wsf + 256);                     // 1024 ints
    unsigned short* M = (unsigned short*)((char*)d_ws + 8192);  // 8.39 MB bf16

    crf_score_kernel<<<BB, 64, 0, stream>>>(emissions, transitions, start_t,
                                            end_t, tags, score);
    crf_chunk_kernel<<<256, 256, 0, stream>>>(emissions, transitions, M, eoffs);
    crf_combine_kernel<<<BB, 64, 0, stream>>>(emissions, start_t, end_t, M,
                                              eoffs, score, res);
    crf_reduce_kernel<<<1, 64, 0, stream>>>(res, (float*)d_out);
}

// Round 4
// 67.449 us; speedup vs baseline: 2.8648x; 1.6470x over previous
//
#include <hip/hip_runtime.h>

// CRF loss: mean_b( log Z_b - score_b ),  B=128, S=512, T=64 (mask all-ones).
//
// Parallel associative scan: alpha_511 = alpha_0 * PROD_i (E * diag(eem_i)).
// Phase 1 (crf_chunk_kernel<CH>): CH chunks x 128 batches waves; each wave
//   computes its chunk's 64x64 transfer matrix via the R1/R2-verified MFMA
//   recurrence on 64 identity basis columns. Loop restructured vs R2:
//   dynamic outer loop over 8-step groups, macro-expanded inner steps (all
//   register indices compile-time), prefetch ring depth 4. No barriers/LDS.
// Phase 2 (crf_combine_kernel<CH>): one wave per batch: path score (fused) +
//   chain alpha through the CH stored bf16 matrices, logsumexp with end_t.

#define BB 128
#define SS 512
#define TT 64

typedef float f32x4 __attribute__((ext_vector_type(4)));
typedef short s16x8 __attribute__((ext_vector_type(8)));
typedef unsigned int u32x4 __attribute__((ext_vector_type(4)));

#define MFMA16(a, b, c) __builtin_amdgcn_mfma_f32_16x16x32_bf16((a), (b), (c), 0, 0, 0)

#define LOG2E 1.4426950408889634f
#define LN2   0.6931471805599453f

__device__ __forceinline__ unsigned pack_bf16_trunc(float hi, float lo) {
    return __builtin_amdgcn_perm(__float_as_uint(hi), __float_as_uint(lo), 0x07060302u);
}
__device__ __forceinline__ unsigned short bf16_rne(float x) {
    unsigned u = __float_as_uint(x);
    u += 0x7FFFu + ((u >> 16) & 1u);
    return (unsigned short)(u >> 16);
}
__device__ __forceinline__ float rdlane(float v, int lane) {
    return __uint_as_float(__builtin_amdgcn_readlane(__float_as_uint(v), lane));
}

// ---------------- Phase 1 ----------------
template<int L>
__device__ __forceinline__ void chunk_body(
    const float* __restrict__ emb, const int sbase, const s16x8 A[4][2],
    unsigned short* __restrict__ Mout, int* __restrict__ eoff_out,
    const int g, const int m, const int l)
{
    constexpr int FB = (L - 1) / 8;      // full 8-step groups
    constexpr int TL = L - 8 * FB;       // tail steps (7 or 8)
    const f32x4 Z = {0.f, 0.f, 0.f, 0.f};
    union BU { s16x8 v; unsigned u[4]; };
    BU Blo[4], Bhi[4];
    #pragma unroll
    for (int nb = 0; nb < 4; ++nb) {
        const int K = 16 * nb + m;
        #pragma unroll
        for (int r = 0; r < 4; ++r) {
            int k0 = 8 * g + 2 * r;
            Blo[nb].u[r] = ((k0 == K) ? 0x3F80u : 0u) | ((k0 + 1 == K) ? 0x3F800000u : 0u);
            int k1 = 32 + 8 * g + 2 * r;
            Bhi[nb].u[r] = ((k1 == K) ? 0x3F80u : 0u) | ((k1 + 1 == K) ? 0x3F800000u : 0u);
        }
    }

    const float* embg = emb + 8 * g;
    f32x4 raw[4][4];
    #pragma unroll
    for (int i = 0; i < 4; ++i) {
        const float* p = embg + (size_t)(sbase + i) * TT;
        raw[i][0] = *(const f32x4*)(p);
        raw[i][1] = *(const f32x4*)(p + 4);
        raw[i][2] = *(const f32x4*)(p + 32);
        raw[i][3] = *(const f32x4*)(p + 36);
    }
    f32x4 dfin[4][4];
    int eoff = 0, epend = 0;

#define NBODY(NB, RESC) do {                                                      \
    f32x4 c0 = MFMA16(A[0][0], Blo[NB].v, Z);                                     \
    f32x4 c1 = MFMA16(A[1][0], Blo[NB].v, Z);                                     \
    f32x4 c2 = MFMA16(A[2][0], Blo[NB].v, Z);                                     \
    f32x4 c3 = MFMA16(A[3][0], Blo[NB].v, Z);                                     \
    c0 = MFMA16(A[0][1], Bhi[NB].v, c0);                                          \
    c1 = MFMA16(A[1][1], Bhi[NB].v, c1);                                          \
    c2 = MFMA16(A[2][1], Bhi[NB].v, c2);                                          \
    c3 = MFMA16(A[3][1], Bhi[NB].v, c3);                                          \
    c0 *= CUR0; c1 *= CUR1; c2 *= CUR2; c3 *= CUR3;                               \
    if (RESC) {                                                                   \
        mx = fmaxf(mx, fmaxf(fmaxf(fmaxf(c0[0], c0[1]), fmaxf(c0[2], c0[3])),     \
                             fmaxf(fmaxf(c1[0], c1[1]), fmaxf(c1[2], c1[3]))));   \
        mx = fmaxf(mx, fmaxf(fmaxf(fmaxf(c2[0], c2[1]), fmaxf(c2[2], c2[3])),     \
                             fmaxf(fmaxf(c3[0], c3[1]), fmaxf(c3[2], c3[3]))));   \
    }                                                                             \
    Blo[NB].u[0] = pack_bf16_trunc(c0[1], c0[0]);                                 \
    Blo[NB].u[1] = pack_bf16_trunc(c0[3], c0[2]);                                 \
    Blo[NB].u[2] = pack_bf16_trunc(c1[1], c1[0]);                                 \
    Blo[NB].u[3] = pack_bf16_trunc(c1[3], c1[2]);                                 \
    Bhi[NB].u[0] = pack_bf16_trunc(c2[1], c2[0]);                                 \
    Bhi[NB].u[1] = pack_bf16_trunc(c2[3], c2[2]);                                 \
    Bhi[NB].u[2] = pack_bf16_trunc(c3[1], c3[0]);                                 \
    Bhi[NB].u[3] = pack_bf16_trunc(c3[3], c3[2]);                                 \
} while (0)

#define CURBLK(SL)                                                                \
    f32x4 r0 = raw[SL][0], r1 = raw[SL][1], r2 = raw[SL][2], r3 = raw[SL][3];     \
    const float fne = -(float)epend; epend = 0;                                   \
    f32x4 CUR0, CUR1, CUR2, CUR3;                                                 \
    CUR0[0] = exp2f(fmaf(r0[0], LOG2E, fne));                                     \
    CUR0[1] = exp2f(fmaf(r0[1], LOG2E, fne));                                     \
    CUR0[2] = exp2f(fmaf(r0[2], LOG2E, fne));                                     \
    CUR0[3] = exp2f(fmaf(r0[3], LOG2E, fne));                                     \
    CUR1[0] = exp2f(fmaf(r1[0], LOG2E, fne));                                     \
    CUR1[1] = exp2f(fmaf(r1[1], LOG2E, fne));                                     \
    CUR1[2] = exp2f(fmaf(r1[2], LOG2E, fne));                                     \
    CUR1[3] = exp2f(fmaf(r1[3], LOG2E, fne));                                     \
    CUR2[0] = exp2f(fmaf(r2[0], LOG2E, fne));                                     \
    CUR2[1] = exp2f(fmaf(r2[1], LOG2E, fne));                                     \
    CUR2[2] = exp2f(fmaf(r2[2], LOG2E, fne));                                     \
    CUR2[3] = exp2f(fmaf(r2[3], LOG2E, fne));                                     \
    CUR3[0] = exp2f(fmaf(r3[0], LOG2E, fne));                                     \
    CUR3[1] = exp2f(fmaf(r3[1], LOG2E, fne));                                     \
    CUR3[2] = exp2f(fmaf(r3[2], LOG2E, fne));                                     \
    CUR3[3] = exp2f(fmaf(r3[3], LOG2E, fne));

#define DOSTEP(SL, RESC, PRE, SIDX) do {                                          \
    CURBLK(SL)                                                                    \
    if (PRE) {                                                                    \
        const float* p_ = embg + (size_t)(SIDX) * TT;                             \
        raw[SL][0] = *(const f32x4*)(p_);                                         \
        raw[SL][1] = *(const f32x4*)(p_ + 4);                                     \
        raw[SL][2] = *(const f32x4*)(p_ + 32);                                    \
        raw[SL][3] = *(const f32x4*)(p_ + 36);                                    \
    }                                                                             \
    float mx = 0.f;                                                               \
    NBODY(0, RESC); NBODY(1, RESC); NBODY(2, RESC); NBODY(3, RESC);               \
    if (RESC) {                                                                   \
        mx = fmaxf(mx, __shfl_xor(mx, 1, 64));                                    \
        mx = fmaxf(mx, __shfl_xor(mx, 2, 64));                                    \
        mx = fmaxf(mx, __shfl_xor(mx, 4, 64));                                    \
        mx = fmaxf(mx, __shfl_xor(mx, 8, 64));                                    \
        mx = fmaxf(mx, __shfl_xor(mx, 16, 64));                                   \
        mx = fmaxf(mx, __shfl_xor(mx, 32, 64));                                   \
        int e_ = (__float_as_int(mx) >> 23) - 127;                                \
        eoff += e_;                                                               \
        epend = e_;                                                               \
    }                                                                             \
} while (0)

#define DOSTEPL(SL) do {                                                          \
    CURBLK(SL)                                                                    \
    _Pragma("unroll")                                                             \
    for (int nb = 0; nb < 4; ++nb) {                                              \
        f32x4 c0 = MFMA16(A[0][0], Blo[nb].v, Z);                                 \
        f32x4 c1 = MFMA16(A[1][0], Blo[nb].v, Z);                                 \
        f32x4 c2 = MFMA16(A[2][0], Blo[nb].v, Z);                                 \
        f32x4 c3 = MFMA16(A[3][0], Blo[nb].v, Z);                                 \
        c0 = MFMA16(A[0][1], Bhi[nb].v, c0);                                      \
        c1 = MFMA16(A[1][1], Bhi[nb].v, c1);                                      \
        c2 = MFMA16(A[2][1], Bhi[nb].v, c2);                                      \
        c3 = MFMA16(A[3][1], Bhi[nb].v, c3);                                      \
        dfin[nb][0] = c0 * CUR0;                                                  \
        dfin[nb][1] = c1 * CUR1;                                                  \
        dfin[nb][2] = c2 * CUR2;                                                  \
        dfin[nb][3] = c3 * CUR3;                                                  \
    }                                                                             \
} while (0)

    #pragma unroll 1
    for (int ob = 0; ob < FB; ++ob) {
        const int sb4 = sbase + 8 * ob + 4;
        DOSTEP(0, 0, 1, sb4 + 0);
        DOSTEP(1, 0, 1, sb4 + 1);
        DOSTEP(2, 0, 1, sb4 + 2);
        DOSTEP(3, 0, 1, sb4 + 3);
        DOSTEP(0, 0, 1, sb4 + 4);
        DOSTEP(1, 0, 1, sb4 + 5);
        DOSTEP(2, 0, 1, sb4 + 6);
        DOSTEP(3, 1, 1, sb4 + 7);
    }
    {
        const int sb4 = sbase + 8 * FB + 4;
        if constexpr (TL == 8) {
            DOSTEP(0, 0, 1, sb4 + 0);
            DOSTEP(1, 0, 1, sb4 + 1);
            DOSTEP(2, 0, 1, sb4 + 2);
            DOSTEP(3, 0, 1, sb4 + 3);
            DOSTEP(0, 0, 0, 0);
            DOSTEP(1, 0, 0, 0);
            DOSTEP(2, 0, 0, 0);
            DOSTEPL(3);
        } else {  // TL == 7
            DOSTEP(0, 0, 1, sb4 + 0);
            DOSTEP(1, 0, 1, sb4 + 1);
            DOSTEP(2, 0, 1, sb4 + 2);
            DOSTEP(3, 0, 0, 0);
            DOSTEP(0, 0, 0, 0);
            DOSTEP(1, 0, 0, 0);
            DOSTEPL(2);
        }
    }
#undef DOSTEPL
#undef DOSTEP
#undef CURBLK
#undef NBODY

    // epilogue: exact-pow2 normalize, store M[k][j] bf16
    float mx = 0.f;
    #pragma unroll
    for (int nb = 0; nb < 4; ++nb)
        #pragma unroll
        for (int t = 0; t < 4; ++t) {
            f32x4 v = dfin[nb][t];
            mx = fmaxf(mx, fmaxf(fmaxf(v[0], v[1]), fmaxf(v[2], v[3])));
        }
    #pragma unroll
    for (int sh = 1; sh < 64; sh <<= 1) mx = fmaxf(mx, __shfl_xor(mx, sh, 64));
    int e = (__float_as_int(mx) >> 23) - 127;
    eoff += e;
    const float scl = __int_as_float((127 - e) << 23);
    #pragma unroll
    for (int nb = 0; nb < 4; ++nb) {
        f32x4 d0 = dfin[nb][0] * scl, d1 = dfin[nb][1] * scl;
        f32x4 d2 = dfin[nb][2] * scl, d3 = dfin[nb][3] * scl;
        const int row = (16 * nb + m) * TT;
        u32x4 w0, w1;
        w0[0] = pack_bf16_trunc(d0[1], d0[0]);
        w0[1] = pack_bf16_trunc(d0[3], d0[2]);
        w0[2] = pack_bf16_trunc(d1[1], d1[0]);
        w0[3] = pack_bf16_trunc(d1[3], d1[2]);
        w1[0] = pack_bf16_trunc(d2[1], d2[0]);
        w1[1] = pack_bf16_trunc(d2[3], d2[2]);
        w1[2] = pack_bf16_trunc(d3[1], d3[0]);
        w1[3] = pack_bf16_trunc(d3[3], d3[2]);
        *(u32x4*)(Mout + row + 8 * g)      = w0;
        *(u32x4*)(Mout + row + 32 + 8 * g) = w1;
    }
    if (l == 0) *eoff_out = eoff;
}

template<int CH>
__global__ __launch_bounds__(256, 2) void crf_chunk_kernel(
    const float* __restrict__ emissions, const float* __restrict__ transitions,
    unsigned short* __restrict__ M, int* __restrict__ eoffs)
{
    constexpr int SC = SS / CH;
    const int tid = threadIdx.x;
    const int l = tid & 63;
    const int w = tid >> 6;
    const int g = l >> 4;
    const int m = l & 15;
    const int b = blockIdx.x / (CH / 4);
    const int c = (blockIdx.x % (CH / 4)) * 4 + w;
    const float* emb = emissions + (size_t)b * SS * TT;

    // A fragments (verified): A[t][h] elem j = bf16(exp(trans[k][ps])),
    // k = 32h + 8g + j, ps = 8*(m>>2) + 4*(t&1) + (m&3) + 32*(t>>1)
    s16x8 A[4][2];
    #pragma unroll
    for (int t = 0; t < 4; ++t) {
        const int ps = 8 * (m >> 2) + 4 * (t & 1) + (m & 3) + 32 * (t >> 1);
        #pragma unroll
        for (int h = 0; h < 2; ++h) {
            union { s16x8 v; unsigned short s[8]; } u;
            #pragma unroll
            for (int j = 0; j < 8; ++j) {
                int k = 32 * h + 8 * g + j;
                u.s[j] = bf16_rne(exp2f(transitions[k * TT + ps] * LOG2E));
            }
            A[t][h] = u.v;
        }
    }

    unsigned short* Mout = M + (size_t)(b * CH + c) * (TT * TT);
    int* eo = eoffs + b * CH + c;
    const int sbase = SC * c + 1;
    if (c == CH - 1) chunk_body<SC - 1>(emb, sbase, A, Mout, eo, g, m, l);
    else             chunk_body<SC>(emb, sbase, A, Mout, eo, g, m, l);
}

// ---------------- Phase 2: score (fused) + chain + logsumexp ----------------
template<int CH>
__global__ __launch_bounds__(64) void crf_combine_kernel(
    const float* __restrict__ emissions, const float* __restrict__ transitions,
    const float* __restrict__ start_t, const float* __restrict__ end_t,
    const int* __restrict__ tags, const unsigned short* __restrict__ M,
    const int* __restrict__ eoffs, float* __restrict__ res)
{
    const int b = blockIdx.x;
    const int j = threadIdx.x;
    const float* em = emissions + (size_t)b * SS * TT;

    // path score
    float sc = 0.f;
    #pragma unroll
    for (int r = 0; r < SS / TT; ++r) {
        int i = j + r * TT;
        int cur = tags[b * SS + i];
        if (i > 0) {
            int prev = tags[b * SS + i - 1];
            sc += transitions[prev * TT + cur] + em[i * TT + cur];
        } else {
            sc += start_t[cur] + em[cur];
        }
    }
    if (j == 0) sc += end_t[tags[b * SS + SS - 1]];
    #pragma unroll
    for (int s = 1; s < 64; s <<= 1) sc += __shfl_xor(sc, s, 64);

    // chain alpha through CH chunk matrices
    float a = exp2f((start_t[j] + em[j]) * LOG2E);
    int eoff = 0;
    #pragma unroll 1
    for (int c = 0; c < CH; ++c) {
        const unsigned short* Mc = M + (size_t)(b * CH + c) * (TT * TT) + j;
        float acc = 0.f;
        #pragma unroll
        for (int k = 0; k < TT; ++k) {
            float mv = __uint_as_float(((unsigned)Mc[k * TT]) << 16);
            acc = fmaf(rdlane(a, k), mv, acc);
        }
        float mxv = acc;
        #pragma unroll
        for (int sh = 1; sh < 64; sh <<= 1) mxv = fmaxf(mxv, __shfl_xor(mxv, sh, 64));
        int e = (__float_as_int(mxv) >> 23) - 127;
        a = acc * __int_as_float((127 - e) << 23);
        eoff += e + eoffs[b * CH + c];
    }
    float v = a * exp2f(end_t[j] * LOG2E);
    #pragma unroll
    for (int sh = 1; sh < 64; sh <<= 1) v += __shfl_xor(v, sh, 64);
    if (j == 0) res[b] = (log2f(v) + (float)eoff) * LN2 - sc;
}

// ---------------- final mean ----------------
__global__ __launch_bounds__(64) void crf_reduce_kernel(
    const float* __restrict__ res, float* __restrict__ out)
{
    int l = threadIdx.x;
    float v = res[l] + res[l + 64];
    #pragma unroll
    for (int s = 1; s < 64; s <<= 1) v += __shfl_xor(v, s, 64);
    if (l == 0) out[0] = v * (1.0f / (float)BB);
}

extern "C" void kernel_launch(void* const* d_in, const int* in_sizes, int n_in,
                              void* d_out, int out_size, void* d_ws, size_t ws_size,
                              hipStream_t stream) {
    const float* emissions   = (const float*)d_in[0];
    const float* transitions = (const float*)d_in[1];
    const float* start_t     = (const float*)d_in[2];
    const float* end_t       = (const float*)d_in[3];
    const int*   tags        = (const int*)d_in[4];

    float* res   = (float*)d_ws;                              // 128 floats
    int*   eoffs = (int*)((char*)d_ws + 512);                 // <= 2048 ints
    unsigned short* M = (unsigned short*)((char*)d_ws + 16384);

    const size_t need16 = 16384 + (size_t)BB * 16 * TT * TT * 2;  // ~16.8 MB
    if (ws_size >= need16) {
        crf_chunk_kernel<16><<<BB * 4, 256, 0, stream>>>(emissions, transitions, M, eoffs);
        crf_combine_kernel<16><<<BB, 64, 0, stream>>>(emissions, transitions, start_t,
                                                      end_t, tags, M, eoffs, res);
    } else {
        crf_chunk_kernel<8><<<BB * 2, 256, 0, stream>>>(emissions, transitions, M, eoffs);
        crf_combine_kernel<8><<<BB, 64, 0, stream>>>(emissions, transitions, start_t,
                                                     end_t, tags, M, eoffs, res);
    }
    crf_reduce_kernel<<<1, 64, 0, stream>>>(res, (float*)d_out);
}